// Round 10
// baseline (213.973 us; speedup 1.0000x reference)
//
#include <hip/hip_runtime.h>

// KMeans assignment: costs[i] = min_k ||x_i-c_k||^2, indices[i] = argmin_k.
// argmin over k of (c2[k] - 2*dot(x,c_k)); x2 additive, added at the end.
// Cross term via split-f16 3-pass MFMA (xh.ch + xl.ch + xh.cl), err ~1e-6.
// R15: cut total executed cycles (scheduling is compiler-invariant: R9/R12/
// R14 all produced identical codegen; MfmaUtil+VALUBusy ~90% sum-capped).
//  - MFMA shape 16x16x32 -> 32x32x16: 12 instead of 24 MFMA/chunk, ~11%
//    faster pipe (2178 vs 1955 TF ubench): 124 -> 111 exec cyc/chunk.
//    Operand mapping generalizes the proven 16x16 pattern (row/col =
//    lane&31, k = (lane>>5)*8+j) -> SAME prep layout, SAME A LDS layout;
//    only the k-group select changes ((lane>>4) -> ks*2+(lane>>5)).
//    C/D: col=lane&31, row=(reg&3)+8*(reg>>2)+4*(lane>>5)  [m74/m101].
//  - Prefetch machinery deleted (compiler sinks loads regardless; the 16
//    bhc-rotate v_movs/chunk were pure VALU waste). B transient from L2.
//  - LDS addr: idx = ((g<<9)+rowoff)^((g&7)<<3), rowoff lane-const -> 2
//    addr computations/chunk (was 4 with more ops each).
// Kept: MT=64 4-wave barrier-free loop; A XOR-swizzle (conflicts 3.68M->
// 8.2K); byte-offset vb; setprio; (256,4).
// Known-bad: pinned B dbuf (R6/R10 spill); packed-key argmin (R7 near-tie
// flips); mid-chunk barrier (R8 -13%); sched_barrier pins (R9 spill).
// N=131072, D=128, K=1024.  d_out = [costs (N f32), indices-as-f32 (N)].

typedef _Float16 f16x8  __attribute__((ext_vector_type(8)));
typedef float    f32x16 __attribute__((ext_vector_type(16)));
typedef unsigned short u16;

constexpr int N = 131072, D = 128, K = 1024;
constexpr int MT = 64;    // points per block

union H2U { _Float16 h; unsigned short u; };

// ---- prep: centers -> hi/lo f16 in fragment-major tiled layout + exact c2 ----
// ushort idx: (((cb*4 + kc)*4 + q)*128 + c%128)*8 + j, k = kc*32 + q*8 + j
__global__ void prep_centers(const float* __restrict__ centers,
                             u16* __restrict__ Bh, u16* __restrict__ Bl,
                             float* __restrict__ c2) {
  const int wave = threadIdx.x >> 6, lane = threadIdx.x & 63;
  const int c = blockIdx.x * 4 + wave;          // one wave per center
  const float2 v = ((const float2*)(centers + (size_t)c * D))[lane];
  float s = v.x * v.x + v.y * v.y;
  #pragma unroll
  for (int off = 32; off; off >>= 1) s += __shfl_xor(s, off, 64);
  if (lane == 0) c2[c] = s;

  H2U h0, h1, l0, l1;
  h0.h = (_Float16)v.x;  l0.h = (_Float16)(v.x - (float)h0.h);
  h1.h = (_Float16)v.y;  l1.h = (_Float16)(v.y - (float)h1.h);
  const int cb = c >> 7, cm = c & 127;
  const int kc = lane >> 4, q = (lane >> 2) & 3, j0 = (lane & 3) * 2;
  const size_t off = (((size_t)(cb * 4 + kc) * 4 + q) * 128 + cm) * 8 + j0;
  *(unsigned*)(Bh + off) = (unsigned)h0.u | ((unsigned)h1.u << 16);
  *(unsigned*)(Bl + off) = (unsigned)l0.u | ((unsigned)l1.u << 16);
}

// ---- main: 64 pts x 1024 centers per block; wave tile 32x64 (2x2 waves) ----
__global__ __launch_bounds__(256, 4) void kmeans_mfma(
    const float* __restrict__ x,
    const u16* __restrict__ Bh_g, const u16* __restrict__ Bl_g,
    const float* __restrict__ c2g,
    float* __restrict__ out_cost, float* __restrict__ out_idx)
{
  // 33 KB: Ah [0,8192) u16, Al [8192,16384), red [16384,16896)
  __shared__ __align__(16) u16 smem[16896];
  u16* Ah = smem;            // [g16][m64][j8] swizzled  16 KB
  u16* Al = smem + 8192;     //                          16 KB

  const int tid = threadIdx.x;
  const int wave = tid >> 6, lane = tid & 63;
  const int wr = wave >> 1, wc = wave & 1;    // wave row/col in 2x2
  const int c32 = lane & 31, q2 = lane >> 5;
  const int m0 = blockIdx.x * MT;

  // ---- stage A tile: fp32 -> (hi,lo) f16, XOR-swizzled tiled layout ----
  #pragma unroll
  for (int i = 0; i < 8; ++i) {
    const int flat = i * 256 + tid;            // 2048 float4s = 64x128 floats
    const int m = flat >> 5, c4 = flat & 31, k0 = c4 * 4;
    const float4 v = *(const float4*)(x + (size_t)(m0 + m) * D + k0);
    const int g = k0 >> 3;                     // k-group in [0,16)
    const int j0 = k0 & 7;                     // 0 or 4
    const float vv[4] = {v.x, v.y, v.z, v.w};
    H2U h[4], l[4];
    #pragma unroll
    for (int z = 0; z < 4; ++z) {
      h[z].h = (_Float16)vv[z];
      l[z].h = (_Float16)(vv[z] - (float)h[z].h);
    }
    const int off = ((g * 64 + m) * 8 + j0) ^ ((g & 7) << 3);
    uint2 hp, lp;
    hp.x = h[0].u | ((unsigned)h[1].u << 16); hp.y = h[2].u | ((unsigned)h[3].u << 16);
    lp.x = l[0].u | ((unsigned)l[1].u << 16); lp.y = l[2].u | ((unsigned)l[3].u << 16);
    *(uint2*)(Ah + off) = hp;
    *(uint2*)(Al + off) = lp;
  }
  __syncthreads();   // A visible; NO barrier in main loop after this

  // ---- x2 per point (thread tid<64 owns m=tid); A persists in LDS ----
  float x2m = 0.f;
  if (tid < MT) {
    #pragma unroll
    for (int g = 0; g < 16; ++g) {
      const int off = ((g * 64 + tid) * 8) ^ ((g & 7) << 3);
      const f16x8 hv = *(const f16x8*)(Ah + off);
      const f16x8 lv = *(const f16x8*)(Al + off);
      #pragma unroll
      for (int e = 0; e < 8; ++e) {
        const float xv = (float)hv[e] + (float)lv[e];
        x2m += xv * xv;
      }
    }
  }

  // B addressing (bytes): frag(cc,ks,u) at
  //   cc*8192 + (ks*2+q2)*2048 + (wc*64 + u*32 + c32)*16
  const char* BhB = (const char*)Bh_g;
  const char* BlB = (const char*)Bl_g;
  unsigned vb = (unsigned)(q2 * 2048 + (wc * 64 + c32) * 16);

  // A LDS addressing (u16 idx): frag(kc,ks) at ((g<<9)+rowoff)^((g&7)<<3),
  //   g = kc*4 + ks*2 + q2, rowoff = (wr*32+c32)*8 (lane-constant)
  const int rowoff = (wr * 32 + c32) * 8;

  float bestV[16]; int bestI[16];
  #pragma unroll
  for (int r = 0; r < 16; ++r) { bestV[r] = 3.4e38f; bestI[r] = 0; }

  #pragma unroll 1
  for (int ct = 0; ct < 8; ++ct) {
    f32x16 acc[2];
    #pragma unroll
    for (int u = 0; u < 2; ++u)
      #pragma unroll
      for (int r = 0; r < 16; ++r) acc[u][r] = 0.f;

    // c2 for this ct tile (2 cols/lane), direct from L2
    float c2v[2];
    #pragma unroll
    for (int u = 0; u < 2; ++u)
      c2v[u] = c2g[ct * 128 + wc * 64 + u * 32 + c32];

    #pragma unroll 1
    for (int kc = 0; kc < 4; ++kc) {
      // transient B fragments from L2 (8 x 16B per chunk)
      f16x8 bh[2][2], bl[2][2];
      #pragma unroll
      for (int ks = 0; ks < 2; ++ks)
        #pragma unroll
        for (int u = 0; u < 2; ++u) {
          bh[ks][u] = *(const f16x8*)(BhB + vb + ks * 4096 + u * 512);
          bl[ks][u] = *(const f16x8*)(BlB + vb + ks * 4096 + u * 512);
        }

      // A fragments from LDS (4 x ds_read_b128)
      f16x8 ah[2], al[2];
      #pragma unroll
      for (int ks = 0; ks < 2; ++ks) {
        const int g = kc * 4 + ks * 2 + q2;
        const int idx = ((g << 9) + rowoff) ^ ((g & 7) << 3);
        ah[ks] = *(const f16x8*)(Ah + idx);
        al[ks] = *(const f16x8*)(Al + idx);
      }

      // 3-pass split-f16: 12 MFMA (32x32x16) per chunk
      __builtin_amdgcn_s_setprio(1);
      #pragma unroll
      for (int u = 0; u < 2; ++u)
        #pragma unroll
        for (int ks = 0; ks < 2; ++ks)
          acc[u] = __builtin_amdgcn_mfma_f32_32x32x16_f16(ah[ks], bh[ks][u], acc[u], 0, 0, 0);
      #pragma unroll
      for (int u = 0; u < 2; ++u)
        #pragma unroll
        for (int ks = 0; ks < 2; ++ks)
          acc[u] = __builtin_amdgcn_mfma_f32_32x32x16_f16(al[ks], bh[ks][u], acc[u], 0, 0, 0);
      #pragma unroll
      for (int u = 0; u < 2; ++u)
        #pragma unroll
        for (int ks = 0; ks < 2; ++ks)
          acc[u] = __builtin_amdgcn_mfma_f32_32x32x16_f16(ah[ks], bl[ks][u], acc[u], 0, 0, 0);
      __builtin_amdgcn_s_setprio(0);

      vb += 8192;
    }

    // epilogue: s = c2 - 2*dot; running min (n strictly increasing per r)
    #pragma unroll
    for (int u = 0; u < 2; ++u) {
      const int n = ct * 128 + wc * 64 + u * 32 + c32;
      #pragma unroll
      for (int r = 0; r < 16; ++r) {
        const float s = __builtin_fmaf(-2.f, acc[u][r], c2v[u]);
        if (s < bestV[r]) { bestV[r] = s; bestI[r] = n; }
      }
    }
  }

  // ---- reduce across the 32 lanes (c32) sharing the same rows ----
  #pragma unroll
  for (int r = 0; r < 16; ++r) {
    float v = bestV[r]; int idx = bestI[r];
    #pragma unroll
    for (int off = 1; off < 32; off <<= 1) {
      const float ov = __shfl_xor(v, off, 64);
      const int   oi = __shfl_xor(idx, off, 64);
      if (ov < v || (ov == v && oi < idx)) { v = ov; idx = oi; }
    }
    bestV[r] = v; bestI[r] = idx;
  }

  float* redV = (float*)(smem + 16384);  // 512 B, disjoint from A
  int*   redI = (int*)(smem + 16640);    // 512 B
  if (c32 == 0) {
    #pragma unroll
    for (int r = 0; r < 16; ++r) {
      const int ml = wr * 32 + (r & 3) + 8 * (r >> 2) + 4 * q2;  // C/D row
      redV[ml * 2 + wc] = bestV[r];
      redI[ml * 2 + wc] = bestI[r];
    }
  }
  __syncthreads();   // reduce writes visible
  if (tid < MT) {
    float v = redV[tid * 2]; int idx = redI[tid * 2];
    const float v1 = redV[tid * 2 + 1]; const int i1 = redI[tid * 2 + 1];
    if (v1 < v || (v1 == v && i1 < idx)) { v = v1; idx = i1; }
    float cost = x2m + v;
    if (cost < 0.f) cost = 0.f;          // clamp like reference
    out_cost[m0 + tid] = cost;
    out_idx[m0 + tid]  = (float)idx;
  }
}

extern "C" void kernel_launch(void* const* d_in, const int* in_sizes, int n_in,
                              void* d_out, int out_size, void* d_ws, size_t ws_size,
                              hipStream_t stream) {
  const float* x       = (const float*)d_in[0];
  const float* centers = (const float*)d_in[1];
  u16*   Bh = (u16*)d_ws;                    // 256 KB
  u16*   Bl = Bh + (size_t)K * D;            // 256 KB
  float* c2 = (float*)(Bl + (size_t)K * D);  // 4 KB
  float* out_cost = (float*)d_out;
  float* out_idx  = out_cost + N;

  prep_centers<<<K / 4, 256, 0, stream>>>(centers, Bh, Bl, c2);
  kmeans_mfma<<<N / MT, 256, 0, stream>>>(x, Bh, Bl, c2, out_cost, out_idx);
}

// Round 11
// 181.204 us; speedup vs baseline: 1.1808x; 1.1808x over previous
//
#include <hip/hip_runtime.h>

// KMeans assignment: costs[i] = min_k ||x_i-c_k||^2, indices[i] = argmin_k.
// argmin over k of (c2[k] - 2*dot(x,c_k)); x2 additive, added at the end.
// Cross term via split-f16 3-pass MFMA (xh.ch + xl.ch + xh.cl), err ~1e-6.
// R16: halve B L2 traffic -- wave map 2x2 -> 1x4 (col strips).
//   R13 plateau audit: B from L2 = 4 waves x 32 chunks x 8KB = 1MB/block
//   (wr-pairs read IDENTICAL fragments) x 2048 blocks = 2GB -> 58us at
//   34.5 TB/s aggregate L2. 50us MFMA + 58us L2 == measured 113us: the
//   kernel is L2-BW-serialized on B, which no scheduling change touches
//   (that's why R9/R12/R13/R14 were all neutral).
//   Fix: each wave owns ALL 64 rows x a PRIVATE 32-col strip -> zero
//   inter-wave B duplication: B/block = 512KB = |B|, total 1GB -> ~29us.
//   Cost: A LDS reads double (8 b128/chunk/wave) -- different pipe (LDS
//   vs L2), stays under the MFMA wall. acc stays 8 frags (32 regs, full
//   ILP -- R15's 2-chain 32x32 shape collapsed ILP, reverted).
// Kept: MT=64 barrier-free loop; 16x16x32 shape; transient B (compiler
// sinks loads regardless -- R14 clobber was a no-op); A XOR-swizzle;
// byte-offset vb; setprio; (256,4).
// Known-bad: pinned B dbuf (R6/R10 spill); packed-key argmin (R7); mid-
// chunk barrier (R8); sched_barrier pins (R9); 32x32 shape (R15 -23%).
// N=131072, D=128, K=1024.  d_out = [costs (N f32), indices-as-f32 (N)].

typedef _Float16 f16x8 __attribute__((ext_vector_type(8)));
typedef float    f32x4 __attribute__((ext_vector_type(4)));
typedef unsigned short u16;

constexpr int N = 131072, D = 128, K = 1024;
constexpr int MT = 64;    // points per block

union H2U { _Float16 h; unsigned short u; };

// ---- prep: centers -> hi/lo f16 in fragment-major tiled layout + exact c2 ----
// ushort idx: (((cb*4 + kc)*4 + q)*128 + c%128)*8 + j, k = kc*32 + q*8 + j
__global__ void prep_centers(const float* __restrict__ centers,
                             u16* __restrict__ Bh, u16* __restrict__ Bl,
                             float* __restrict__ c2) {
  const int wave = threadIdx.x >> 6, lane = threadIdx.x & 63;
  const int c = blockIdx.x * 4 + wave;          // one wave per center
  const float2 v = ((const float2*)(centers + (size_t)c * D))[lane];
  float s = v.x * v.x + v.y * v.y;
  #pragma unroll
  for (int off = 32; off; off >>= 1) s += __shfl_xor(s, off, 64);
  if (lane == 0) c2[c] = s;

  H2U h0, h1, l0, l1;
  h0.h = (_Float16)v.x;  l0.h = (_Float16)(v.x - (float)h0.h);
  h1.h = (_Float16)v.y;  l1.h = (_Float16)(v.y - (float)h1.h);
  const int cb = c >> 7, cm = c & 127;
  const int kc = lane >> 4, q = (lane >> 2) & 3, j0 = (lane & 3) * 2;
  const size_t off = (((size_t)(cb * 4 + kc) * 4 + q) * 128 + cm) * 8 + j0;
  *(unsigned*)(Bh + off) = (unsigned)h0.u | ((unsigned)h1.u << 16);
  *(unsigned*)(Bl + off) = (unsigned)l0.u | ((unsigned)l1.u << 16);
}

// ---- main: 64 pts x 1024 centers per block; wave strip 64 rows x 32 cols ----
__global__ __launch_bounds__(256, 4) void kmeans_mfma(
    const float* __restrict__ x,
    const u16* __restrict__ Bh_g, const u16* __restrict__ Bl_g,
    const float* __restrict__ c2g,
    float* __restrict__ out_cost, float* __restrict__ out_idx)
{
  // 34 KB: Ah [0,8192) u16, Al [8192,16384), redV/redI [16384,17408)
  __shared__ __align__(16) u16 smem[17408];
  u16* Ah = smem;            // [g16][m64][j8] swizzled  16 KB
  u16* Al = smem + 8192;     //                          16 KB

  const int tid = threadIdx.x;
  const int wave = tid >> 6, lane = tid & 63;   // wave = col strip [0,4)
  const int q = lane >> 4, ln = lane & 15;
  const int m0 = blockIdx.x * MT;

  // ---- stage A tile: fp32 -> (hi,lo) f16, XOR-swizzled tiled layout ----
  #pragma unroll
  for (int i = 0; i < 8; ++i) {
    const int flat = i * 256 + tid;            // 2048 float4s = 64x128 floats
    const int m = flat >> 5, c4 = flat & 31, k0 = c4 * 4;
    const float4 v = *(const float4*)(x + (size_t)(m0 + m) * D + k0);
    const int g = k0 >> 3;                     // k-group in [0,16)
    const int j0 = k0 & 7;                     // 0 or 4
    const float vv[4] = {v.x, v.y, v.z, v.w};
    H2U h[4], l[4];
    #pragma unroll
    for (int z = 0; z < 4; ++z) {
      h[z].h = (_Float16)vv[z];
      l[z].h = (_Float16)(vv[z] - (float)h[z].h);
    }
    const int off = ((g * 64 + m) * 8 + j0) ^ ((g & 7) << 3);
    uint2 hp, lp;
    hp.x = h[0].u | ((unsigned)h[1].u << 16); hp.y = h[2].u | ((unsigned)h[3].u << 16);
    lp.x = l[0].u | ((unsigned)l[1].u << 16); lp.y = l[2].u | ((unsigned)l[3].u << 16);
    *(uint2*)(Ah + off) = hp;
    *(uint2*)(Al + off) = lp;
  }
  __syncthreads();   // A visible; NO barrier in main loop after this

  // ---- x2 per point (thread tid<64 owns m=tid); A persists in LDS ----
  float x2m = 0.f;
  if (tid < MT) {
    #pragma unroll
    for (int g = 0; g < 16; ++g) {
      const int off = ((g * 64 + tid) * 8) ^ ((g & 7) << 3);
      const f16x8 hv = *(const f16x8*)(Ah + off);
      const f16x8 lv = *(const f16x8*)(Al + off);
      #pragma unroll
      for (int e = 0; e < 8; ++e) {
        const float xv = (float)hv[e] + (float)lv[e];
        x2m += xv * xv;
      }
    }
  }

  // B addressing (bytes): frag(cc,nt) col = wave*32 + nt*16 + ln, k-grp q:
  //   byte = cc*8192 + q*2048 + (wave*32 + nt*16 + ln)*16
  const char* BhB = (const char*)Bh_g;
  const char* BlB = (const char*)Bl_g;
  unsigned vb = (unsigned)(q * 2048 + (wave * 32 + ln) * 16);

  float bestV[16]; int bestI[16];
  #pragma unroll
  for (int b = 0; b < 16; ++b) { bestV[b] = 3.4e38f; bestI[b] = 0; }

  #pragma unroll 1
  for (int ct = 0; ct < 8; ++ct) {
    f32x4 acc[4][2];
    #pragma unroll
    for (int mt = 0; mt < 4; ++mt)
      #pragma unroll
      for (int nt = 0; nt < 2; ++nt)
        acc[mt][nt] = (f32x4){0.f, 0.f, 0.f, 0.f};

    // c2 for this ct tile (2 cols/lane in this wave's strip), from L2
    float c2v[2];
    #pragma unroll
    for (int nt = 0; nt < 2; ++nt)
      c2v[nt] = c2g[ct * 128 + wave * 32 + nt * 16 + ln];

    #pragma unroll 1
    for (int kc = 0; kc < 4; ++kc) {
      // transient B fragments from L2: 4 x 16B per chunk (was 8 -- the
      // wave's private 32-col strip needs only 2 frags x hi/lo)
      f16x8 bh[2], bl[2];
      #pragma unroll
      for (int nt = 0; nt < 2; ++nt) {
        bh[nt] = *(const f16x8*)(BhB + vb + nt * 256);
        bl[nt] = *(const f16x8*)(BlB + vb + nt * 256);
      }

      // A fragments from LDS: all 64 rows (4 m-frags x hi/lo = 8 b128)
      f16x8 ah[4], al[4];
      const int gg = kc * 4 + q;
      #pragma unroll
      for (int mt = 0; mt < 4; ++mt) {
        const int moff = ((gg * 64 + mt * 16 + ln) * 8) ^ ((gg & 7) << 3);
        ah[mt] = *(const f16x8*)(Ah + moff);
        al[mt] = *(const f16x8*)(Al + moff);
      }

      // 3-pass split-f16: 24 MFMA per chunk, 8 independent acc chains
      __builtin_amdgcn_s_setprio(1);
      #pragma unroll
      for (int mt = 0; mt < 4; ++mt)
        #pragma unroll
        for (int nt = 0; nt < 2; ++nt)
          acc[mt][nt] = __builtin_amdgcn_mfma_f32_16x16x32_f16(ah[mt], bh[nt], acc[mt][nt], 0, 0, 0);
      #pragma unroll
      for (int mt = 0; mt < 4; ++mt)
        #pragma unroll
        for (int nt = 0; nt < 2; ++nt)
          acc[mt][nt] = __builtin_amdgcn_mfma_f32_16x16x32_f16(al[mt], bh[nt], acc[mt][nt], 0, 0, 0);
      #pragma unroll
      for (int mt = 0; mt < 4; ++mt)
        #pragma unroll
        for (int nt = 0; nt < 2; ++nt)
          acc[mt][nt] = __builtin_amdgcn_mfma_f32_16x16x32_f16(ah[mt], bl[nt], acc[mt][nt], 0, 0, 0);
      __builtin_amdgcn_s_setprio(0);

      vb += 8192;
    }

    // epilogue: s = c2 - 2*dot; running min (n strictly increasing per b)
    #pragma unroll
    for (int nt = 0; nt < 2; ++nt) {
      const int n = ct * 128 + wave * 32 + nt * 16 + ln;
      #pragma unroll
      for (int mt = 0; mt < 4; ++mt)
        #pragma unroll
        for (int r = 0; r < 4; ++r) {
          const float s = __builtin_fmaf(-2.f, acc[mt][nt][r], c2v[nt]);
          const int b = mt * 4 + r;
          if (s < bestV[b]) { bestV[b] = s; bestI[b] = n; }
        }
    }
  }

  // ---- reduce across the 16 lanes (ln) sharing the same rows ----
  #pragma unroll
  for (int b = 0; b < 16; ++b) {
    float v = bestV[b]; int idx = bestI[b];
    #pragma unroll
    for (int off = 1; off < 16; off <<= 1) {
      const float ov = __shfl_xor(v, off, 64);
      const int   oi = __shfl_xor(idx, off, 64);
      if (ov < v || (ov == v && oi < idx)) { v = ov; idx = oi; }
    }
    bestV[b] = v; bestI[b] = idx;
  }

  // rows per lane: ml = mt*16 + q*4 + r; 4 waves hold disjoint col strips
  float* redV = (float*)(smem + 16384);  // 64 rows x 4 waves = 1 KB
  int*   redI = (int*)(smem + 16896);    // 1 KB (u16 idx 16896? see below)
  // NOTE: redI placed at u16 offset 16896 -> byte 33792; smem has 17408
  // u16 = 34816 B: redV bytes [32768,33792), redI [33792,34816). OK.
  if (ln == 0) {
    #pragma unroll
    for (int b = 0; b < 16; ++b) {
      const int ml = (b >> 2) * 16 + q * 4 + (b & 3);   // row in [0,64)
      redV[ml * 4 + wave] = bestV[b];
      redI[ml * 4 + wave] = bestI[b];
    }
  }
  __syncthreads();   // reduce writes visible
  if (tid < MT) {
    float v = redV[tid * 4]; int idx = redI[tid * 4];
    #pragma unroll
    for (int w = 1; w < 4; ++w) {
      const float v1 = redV[tid * 4 + w]; const int i1 = redI[tid * 4 + w];
      if (v1 < v || (v1 == v && i1 < idx)) { v = v1; idx = i1; }
    }
    float cost = x2m + v;
    if (cost < 0.f) cost = 0.f;          // clamp like reference
    out_cost[m0 + tid] = cost;
    out_idx[m0 + tid]  = (float)idx;
  }
}

extern "C" void kernel_launch(void* const* d_in, const int* in_sizes, int n_in,
                              void* d_out, int out_size, void* d_ws, size_t ws_size,
                              hipStream_t stream) {
  const float* x       = (const float*)d_in[0];
  const float* centers = (const float*)d_in[1];
  u16*   Bh = (u16*)d_ws;                    // 256 KB
  u16*   Bl = Bh + (size_t)K * D;            // 256 KB
  float* c2 = (float*)(Bl + (size_t)K * D);  // 4 KB
  float* out_cost = (float*)d_out;
  float* out_idx  = out_cost + N;

  prep_centers<<<K / 4, 256, 0, stream>>>(centers, Bh, Bl, c2);
  kmeans_mfma<<<N / MT, 256, 0, stream>>>(x, Bh, Bl, c2, out_cost, out_idx);
}